// Round 1
// baseline (1305.957 us; speedup 1.0000x reference)
//
#include <hip/hip_runtime.h>
#include <math.h>

// Problem constants (verified against setup_inputs at launch via in_sizes)
static constexpr int IN_D = 256;
static constexpr int HIDD = 128;
static constexpr int OUTD = 64;

// ---------------------------------------------------------------------------
// init: deg = 1 (self-loop), zero BN-stat accumulators
__global__ void init_kernel(float* __restrict__ deg, double* __restrict__ st0,
                            double* __restrict__ st1, int n) {
    int i = blockIdx.x * 256 + threadIdx.x;
    if (i < n) deg[i] = 1.0f;
    if (i < 128) st0[i] = 0.0;
    if (i < 64)  st1[i] = 0.0;
}

__global__ void deg_kernel(const int* __restrict__ dst, float* __restrict__ deg, int E) {
    int e = blockIdx.x * 256 + threadIdx.x;
    if (e < E) atomicAdd(&deg[dst[e]], 1.0f);
}

__global__ void rsqrt_kernel(float* __restrict__ deg, int n) {
    int i = blockIdx.x * 256 + threadIdx.x;
    if (i < n) deg[i] = rsqrtf(deg[i]);  // deg >= 1 always
}

// ---------------------------------------------------------------------------
// Generic tiled f32 GEMM: C[M,NCOL] = op(A[M,K]) @ W[K,NCOL] (+ bias)
// 64-row tiles, KK=32 k-steps, 4x4 register tiles per thread.
template <int K, int NCOL, bool RELU, bool BIAS>
__global__ __launch_bounds__((NCOL / 4) * 16)
void mm_kernel(const float* __restrict__ A, const float* __restrict__ W,
               const float* __restrict__ bias, float* __restrict__ C, int M) {
    constexpr int MT = 64;
    constexpr int KK = 32;
    constexpr int TPB = (NCOL / 4) * (MT / 4);
    __shared__ float xs[KK][MT + 4];   // k-major staged A tile
    __shared__ float ws[KK][NCOL];     // staged W tile (contiguous)

    const int t = threadIdx.x;
    const int m0 = blockIdx.x * MT;
    const int tc = t % (NCOL / 4);
    const int tr = t / (NCOL / 4);
    const int c0 = tc * 4, r0 = tr * 4;

    float acc[4][4] = {};

    for (int ko = 0; ko < K; ko += KK) {
        // stage A tile, transposed to k-major
        constexpr int NF4 = MT * KK / 4;  // 512 float4
        for (int idx = t; idx < NF4; idx += TPB) {
            int m = idx >> 3;        // KK/4 == 8
            int jk = idx & 7;
            float4 v = make_float4(0.f, 0.f, 0.f, 0.f);
            if (m0 + m < M)
                v = *(const float4*)&A[(size_t)(m0 + m) * K + ko + jk * 4];
            if (RELU) {
                v.x = fmaxf(v.x, 0.f); v.y = fmaxf(v.y, 0.f);
                v.z = fmaxf(v.z, 0.f); v.w = fmaxf(v.w, 0.f);
            }
            xs[jk * 4 + 0][m] = v.x;
            xs[jk * 4 + 1][m] = v.y;
            xs[jk * 4 + 2][m] = v.z;
            xs[jk * 4 + 3][m] = v.w;
        }
        // stage W tile (rows ko..ko+KK-1, all cols -> contiguous chunk)
        constexpr int WF4 = KK * NCOL / 4;
        const float4* Wp = (const float4*)(W + (size_t)ko * NCOL);
        float4* wsp = (float4*)&ws[0][0];
        for (int idx = t; idx < WF4; idx += TPB) wsp[idx] = Wp[idx];
        __syncthreads();

#pragma unroll
        for (int kk = 0; kk < KK; kk++) {
            float4 av = *(const float4*)&xs[kk][r0];
            float4 wv = *(const float4*)&ws[kk][c0];
            acc[0][0] += av.x * wv.x; acc[0][1] += av.x * wv.y;
            acc[0][2] += av.x * wv.z; acc[0][3] += av.x * wv.w;
            acc[1][0] += av.y * wv.x; acc[1][1] += av.y * wv.y;
            acc[1][2] += av.y * wv.z; acc[1][3] += av.y * wv.w;
            acc[2][0] += av.z * wv.x; acc[2][1] += av.z * wv.y;
            acc[2][2] += av.z * wv.z; acc[2][3] += av.z * wv.w;
            acc[3][0] += av.w * wv.x; acc[3][1] += av.w * wv.y;
            acc[3][2] += av.w * wv.z; acc[3][3] += av.w * wv.w;
        }
        __syncthreads();
    }

    float4 b4 = make_float4(0.f, 0.f, 0.f, 0.f);
    if (BIAS) b4 = *(const float4*)&bias[c0];
#pragma unroll
    for (int i = 0; i < 4; i++) {
        int row = m0 + r0 + i;
        if (row < M) {
            float4 o;
            o.x = acc[i][0] + b4.x; o.y = acc[i][1] + b4.y;
            o.z = acc[i][2] + b4.z; o.w = acc[i][3] + b4.w;
            *(float4*)&C[(size_t)row * NCOL + c0] = o;
        }
    }
}

// ---------------------------------------------------------------------------
// GCN self-loop init: agg[i][c] = hW[i][c]*dinv[i]^2 + b[c]
template <int NC>
__global__ void self_init_kernel(const float* __restrict__ hW,
                                 const float* __restrict__ dinv,
                                 const float* __restrict__ b,
                                 float* __restrict__ agg, int n) {
    int i = blockIdx.x * 256 + threadIdx.x;
    if (i < n * NC) {
        int node = i / NC;
        int c = i % NC;
        float di = dinv[node];
        agg[i] = hW[i] * di * di + b[c];
    }
}

// GCN edge scatter: agg[dst] += hW[src] * dinv[src]*dinv[dst]
template <int NC>
__global__ void scatter_kernel(const float* __restrict__ hW,
                               const float* __restrict__ dinv,
                               const int* __restrict__ src,
                               const int* __restrict__ dst,
                               float* __restrict__ agg, int E) {
    int t = blockIdx.x * 256 + threadIdx.x;
    int e = t / NC;
    int c = t % NC;
    if (e < E) {
        int s = src[e], d = dst[e];
        float nrm = dinv[s] * dinv[d];
        atomicAdd(&agg[(size_t)d * NC + c], hW[(size_t)s * NC + c] * nrm);
    }
}

// ---------------------------------------------------------------------------
// Build Wc[64][128] = [W_m0_top | W_m0_bot] so AB = h2 @ Wc gives A|B per node
__global__ void concat_w_kernel(const float* __restrict__ Wm0, float* __restrict__ Wc) {
    int i = blockIdx.x * 256 + threadIdx.x;
    if (i < 64 * 128) {
        int k = i >> 7, j = i & 127;
        Wc[i] = (j < 64) ? Wm0[k * 64 + j] : Wm0[(64 + k) * 64 + (j - 64)];
    }
}

// ---------------------------------------------------------------------------
// BN0 stats: z0[e][c] = A[src][c] + B[dst][c] + bm0[c]; accumulate sum, sumsq
__global__ void stats0_kernel(const float* __restrict__ AB,
                              const int* __restrict__ src,
                              const int* __restrict__ dst,
                              const float* __restrict__ bm0,
                              double* __restrict__ st, int E) {
    int c = threadIdx.x & 63;
    int eg = threadIdx.x >> 6;  // 4 edge-groups per block
    float s1 = 0.f, s2 = 0.f;
    float bm = bm0[c];
    for (int e = blockIdx.x * 4 + eg; e < E; e += gridDim.x * 4) {
        float a = AB[(size_t)src[e] * 128 + c];
        float b = AB[(size_t)dst[e] * 128 + 64 + c];
        float z = a + b + bm;
        s1 += z;
        s2 += z * z;
    }
    __shared__ float r1[256], r2[256];
    r1[threadIdx.x] = s1; r2[threadIdx.x] = s2;
    __syncthreads();
    if (threadIdx.x < 64) {
        float a1 = r1[threadIdx.x] + r1[threadIdx.x + 64] + r1[threadIdx.x + 128] + r1[threadIdx.x + 192];
        float a2 = r2[threadIdx.x] + r2[threadIdx.x + 64] + r2[threadIdx.x + 128] + r2[threadIdx.x + 192];
        atomicAdd(&st[c], (double)a1);
        atomicAdd(&st[64 + c], (double)a2);
    }
}

// s = g*rsqrt(var+eps); t = be - s*mu + s*bm0  (bm0 folded so mlp1 skips it)
__global__ void bnprep0_kernel(const double* __restrict__ st,
                               const float* __restrict__ g, const float* __restrict__ be,
                               const float* __restrict__ bm,
                               float* __restrict__ s0, float* __restrict__ t0, int E) {
    int c = threadIdx.x;
    if (c < 64) {
        double mu = st[c] / (double)E;
        double var = st[64 + c] / (double)E - mu * mu;
        double inv = 1.0 / sqrt(var + 1e-5);
        float s = (float)((double)g[c] * inv);
        float t = (float)((double)be[c] - (double)s * mu + (double)s * (double)bm[c]);
        s0[c] = s; t0[c] = t;
    }
}

// ---------------------------------------------------------------------------
// MLP layer 1: per edge, z0 = A[src]+B[dst]; y0 = relu(s0*z0+t0);
// z1 = y0 @ W_m1 + b_m1  -> store [E,32]
__global__ __launch_bounds__(256)
void mlp1_kernel(const float* __restrict__ AB, const int* __restrict__ src,
                 const int* __restrict__ dst, const float* __restrict__ s0,
                 const float* __restrict__ t0, const float* __restrict__ Wm1,
                 const float* __restrict__ bm1, float* __restrict__ z1, int E) {
    int e = blockIdx.x * 256 + threadIdx.x;
    if (e >= E) return;
    const float* Ar = AB + (size_t)src[e] * 128;
    const float* Br = AB + (size_t)dst[e] * 128 + 64;
    float acc[32];
#pragma unroll
    for (int j = 0; j < 32; j++) acc[j] = bm1[j];

    for (int k = 0; k < 64; k += 4) {
        float4 a4 = *(const float4*)&Ar[k];
        float4 b4 = *(const float4*)&Br[k];
        float4 sv = *(const float4*)&s0[k];
        float4 tv = *(const float4*)&t0[k];
        float y0 = fmaxf(sv.x * (a4.x + b4.x) + tv.x, 0.f);
        float y1 = fmaxf(sv.y * (a4.y + b4.y) + tv.y, 0.f);
        float y2 = fmaxf(sv.z * (a4.z + b4.z) + tv.z, 0.f);
        float y3 = fmaxf(sv.w * (a4.w + b4.w) + tv.w, 0.f);
#pragma unroll
        for (int j = 0; j < 32; j++) {
            acc[j] += y0 * Wm1[(k + 0) * 32 + j];
            acc[j] += y1 * Wm1[(k + 1) * 32 + j];
            acc[j] += y2 * Wm1[(k + 2) * 32 + j];
            acc[j] += y3 * Wm1[(k + 3) * 32 + j];
        }
    }
    float4* zp = (float4*)&z1[(size_t)e * 32];
#pragma unroll
    for (int jj = 0; jj < 8; jj++)
        zp[jj] = make_float4(acc[4 * jj], acc[4 * jj + 1], acc[4 * jj + 2], acc[4 * jj + 3]);
}

// BN1 stats over z1 [E,32]
__global__ void stats1_kernel(const float* __restrict__ z1, double* __restrict__ st, int E) {
    int c = threadIdx.x & 31;
    int eg = threadIdx.x >> 5;  // 8 edge-groups
    float s1 = 0.f, s2 = 0.f;
    for (int e = blockIdx.x * 8 + eg; e < E; e += gridDim.x * 8) {
        float z = z1[(size_t)e * 32 + c];
        s1 += z;
        s2 += z * z;
    }
    __shared__ float r1[256], r2[256];
    r1[threadIdx.x] = s1; r2[threadIdx.x] = s2;
    __syncthreads();
    if (threadIdx.x < 32) {
        float a1 = 0.f, a2 = 0.f;
#pragma unroll
        for (int gq = 0; gq < 8; gq++) { a1 += r1[threadIdx.x + 32 * gq]; a2 += r2[threadIdx.x + 32 * gq]; }
        atomicAdd(&st[c], (double)a1);
        atomicAdd(&st[32 + c], (double)a2);
    }
}

__global__ void bnprep1_kernel(const double* __restrict__ st,
                               const float* __restrict__ g, const float* __restrict__ be,
                               float* __restrict__ s1, float* __restrict__ t1, int E) {
    int c = threadIdx.x;
    if (c < 32) {
        double mu = st[c] / (double)E;
        double var = st[32 + c] / (double)E - mu * mu;
        double inv = 1.0 / sqrt(var + 1e-5);
        float s = (float)((double)g[c] * inv);
        float t = (float)((double)be[c] - (double)s * mu);
        s1[c] = s; t1[c] = t;
    }
}

// MLP layer 2 + sigmoid: out[e] = sigmoid(relu(bn1(z1)) @ W_m2 + b_m2)
__global__ void mlp2_kernel(const float* __restrict__ z1, const float* __restrict__ s1,
                            const float* __restrict__ t1, const float* __restrict__ Wm2,
                            const float* __restrict__ bm2, float* __restrict__ out, int E) {
    int e = blockIdx.x * 256 + threadIdx.x;
    if (e >= E) return;
    const float* zr = z1 + (size_t)e * 32;
    float acc = bm2[0];
#pragma unroll
    for (int k = 0; k < 32; k += 4) {
        float4 z4 = *(const float4*)&zr[k];
        float4 sv = *(const float4*)&s1[k];
        float4 tv = *(const float4*)&t1[k];
        float4 wv = *(const float4*)&Wm2[k];
        acc += fmaxf(sv.x * z4.x + tv.x, 0.f) * wv.x;
        acc += fmaxf(sv.y * z4.y + tv.y, 0.f) * wv.y;
        acc += fmaxf(sv.z * z4.z + tv.z, 0.f) * wv.z;
        acc += fmaxf(sv.w * z4.w + tv.w, 0.f) * wv.w;
    }
    out[e] = 1.f / (1.f + expf(-acc));
}

// ---------------------------------------------------------------------------
extern "C" void kernel_launch(void* const* d_in, const int* in_sizes, int n_in,
                              void* d_out, int out_size, void* d_ws, size_t ws_size,
                              hipStream_t stream) {
    const float* x      = (const float*)d_in[0];
    const int*   eidx   = (const int*)d_in[1];
    const float* W_emb  = (const float*)d_in[2];
    const float* b_emb  = (const float*)d_in[3];
    const float* W_g1   = (const float*)d_in[4];
    const float* b_g1   = (const float*)d_in[5];
    const float* W_g2   = (const float*)d_in[6];
    const float* b_g2   = (const float*)d_in[7];
    const float* W_m0   = (const float*)d_in[8];
    const float* b_m0   = (const float*)d_in[9];
    const float* g_m0   = (const float*)d_in[10];
    const float* be_m0  = (const float*)d_in[11];
    const float* W_m1   = (const float*)d_in[12];
    const float* b_m1   = (const float*)d_in[13];
    const float* g_m1   = (const float*)d_in[14];
    const float* be_m1  = (const float*)d_in[15];
    const float* W_m2   = (const float*)d_in[16];
    const float* b_m2   = (const float*)d_in[17];
    float* out = (float*)d_out;

    const int N = in_sizes[0] / IN_D;   // 50000
    const int E = in_sizes[1] / 2;      // 800000
    const int* src = eidx;
    const int* dst = eidx + E;

    // workspace carve-up (all 256B aligned)
    char* p = (char*)d_ws;
    auto alloc = [&](size_t bytes) {
        void* r = (void*)p;
        p += (bytes + 255) & ~(size_t)255;
        return r;
    };
    float*  deg  = (float*)alloc((size_t)N * 4);                 // -> dinv in place
    float*  B2   = (float*)alloc((size_t)N * HIDD * 4);          // h0, later agg2
    float*  B3   = (float*)alloc((size_t)N * HIDD * 4);          // hW1, later hW2
    float*  B4   = (float*)alloc((size_t)N * HIDD * 4);          // agg1, later AB
    float*  z1   = (float*)alloc((size_t)E * 32 * 4);
    float*  Wc   = (float*)alloc(64 * 128 * 4);
    double* st0  = (double*)alloc(128 * 8);
    double* st1  = (double*)alloc(64 * 8);
    float*  s0   = (float*)alloc(64 * 4);
    float*  t0   = (float*)alloc(64 * 4);
    float*  s1   = (float*)alloc(32 * 4);
    float*  t1   = (float*)alloc(32 * 4);

    float* h0   = B2;  float* agg2 = B2;
    float* hW1  = B3;  float* hW2  = B3;
    float* agg1 = B4;  float* AB   = B4;

    const int nb256N = (N + 255) / 256;

    // degree + norm
    init_kernel<<<nb256N, 256, 0, stream>>>(deg, st0, st1, N);
    deg_kernel<<<(E + 255) / 256, 256, 0, stream>>>(dst, deg, E);
    rsqrt_kernel<<<nb256N, 256, 0, stream>>>(deg, N);
    float* dinv = deg;

    // embedding: h0 = x @ W_emb + b_emb
    mm_kernel<256, 128, false, true><<<(N + 63) / 64, 512, 0, stream>>>(x, W_emb, b_emb, h0, N);

    // GCN1
    mm_kernel<128, 128, false, false><<<(N + 63) / 64, 512, 0, stream>>>(h0, W_g1, nullptr, hW1, N);
    self_init_kernel<128><<<((size_t)N * 128 + 255) / 256, 256, 0, stream>>>(hW1, dinv, b_g1, agg1, N);
    scatter_kernel<128><<<((size_t)E * 128 + 255) / 256, 256, 0, stream>>>(hW1, dinv, src, dst, agg1, E);

    // GCN2 (relu on agg1 fused into staging)
    mm_kernel<128, 64, true, false><<<(N + 63) / 64, 256, 0, stream>>>(agg1, W_g2, nullptr, hW2, N);
    self_init_kernel<64><<<((size_t)N * 64 + 255) / 256, 256, 0, stream>>>(hW2, dinv, b_g2, agg2, N);
    scatter_kernel<64><<<((size_t)E * 64 + 255) / 256, 256, 0, stream>>>(hW2, dinv, src, dst, agg2, E);

    // AB = h2 @ [Wtop|Wbot]  (edge MLP layer-0 factorization)
    concat_w_kernel<<<32, 256, 0, stream>>>(W_m0, Wc);
    mm_kernel<64, 128, false, false><<<(N + 63) / 64, 512, 0, stream>>>(agg2, Wc, nullptr, AB, N);

    // BN0 stats -> scale/shift
    stats0_kernel<<<1024, 256, 0, stream>>>(AB, src, dst, b_m0, st0, E);
    bnprep0_kernel<<<1, 64, 0, stream>>>(st0, g_m0, be_m0, b_m0, s0, t0, E);

    // MLP1 -> z1, BN1 stats -> scale/shift
    mlp1_kernel<<<(E + 255) / 256, 256, 0, stream>>>(AB, src, dst, s0, t0, W_m1, b_m1, z1, E);
    stats1_kernel<<<1024, 256, 0, stream>>>(z1, st1, E);
    bnprep1_kernel<<<1, 32, 0, stream>>>(st1, g_m1, be_m1, s1, t1, E);

    // MLP2 + sigmoid
    mlp2_kernel<<<(E + 255) / 256, 256, 0, stream>>>(z1, s1, t1, W_m2, b_m2, out, E);
}

// Round 3
// 1049.590 us; speedup vs baseline: 1.2443x; 1.2443x over previous
//
#include <hip/hip_runtime.h>
#include <math.h>

static constexpr int IN_D = 256;
static constexpr int HIDD = 128;

// ---------------------------------------------------------------------------
// init: zero dst-histogram and BN-stat accumulators (ws is poisoned each call)
__global__ void init_kernel(int* __restrict__ hist, double* __restrict__ st0,
                            double* __restrict__ st1, int n) {
    int i = blockIdx.x * 256 + threadIdx.x;
    if (i < n) hist[i] = 0;
    if (i < 128) st0[i] = 0.0;
    if (i < 64)  st1[i] = 0.0;
}

__global__ void hist_kernel(const int* __restrict__ dst, int* __restrict__ hist, int E) {
    int e = blockIdx.x * 256 + threadIdx.x;
    if (e < E) atomicAdd(&hist[dst[e]], 1);
}

// Single-block exclusive scan over hist[N] -> rowptr/cursor; dinv = rsqrt(deg+1)
__global__ __launch_bounds__(1024)
void scan_kernel(const int* __restrict__ hist, int* __restrict__ rowptr,
                 int* __restrict__ cursor, float* __restrict__ dinv, int N, int E) {
    __shared__ int lsum[1024];
    const int t = threadIdx.x;
    const int chunk = (N + 1023) >> 10;
    const int lo = t * chunk;
    const int hi = min(N, lo + chunk);
    int s = 0;
    for (int i = lo; i < hi; i++) s += hist[i];
    lsum[t] = s;
    __syncthreads();
    for (int off = 1; off < 1024; off <<= 1) {
        int v = (t >= off) ? lsum[t - off] : 0;
        __syncthreads();
        lsum[t] += v;
        __syncthreads();
    }
    int run = lsum[t] - s;  // exclusive prefix
    for (int i = lo; i < hi; i++) {
        rowptr[i] = run;
        cursor[i] = run;
        dinv[i] = rsqrtf((float)hist[i] + 1.0f);  // +1 self-loop
        run += hist[i];
    }
    if (t == 1023) rowptr[N] = E;
}

__global__ void fill_kernel(const int* __restrict__ src, const int* __restrict__ dst,
                            int* __restrict__ cursor, int* __restrict__ src_sorted, int E) {
    int e = blockIdx.x * 256 + threadIdx.x;
    if (e < E) {
        int pos = atomicAdd(&cursor[dst[e]], 1);
        src_sorted[pos] = src[e];
    }
}

// ---------------------------------------------------------------------------
// Generic tiled f32 GEMM: C[M,NCOL] = op(A[M,K]) @ W[K,NCOL] (+ bias)
template <int K, int NCOL, bool RELU, bool BIAS>
__global__ __launch_bounds__((NCOL / 4) * 16)
void mm_kernel(const float* __restrict__ A, const float* __restrict__ W,
               const float* __restrict__ bias, float* __restrict__ C, int M) {
    constexpr int MT = 64;
    constexpr int KK = 32;
    constexpr int TPB = (NCOL / 4) * (MT / 4);
    __shared__ float xs[KK][MT + 4];
    __shared__ float ws[KK][NCOL];

    const int t = threadIdx.x;
    const int m0 = blockIdx.x * MT;
    const int tc = t % (NCOL / 4);
    const int tr = t / (NCOL / 4);
    const int c0 = tc * 4, r0 = tr * 4;

    float acc[4][4] = {};

    for (int ko = 0; ko < K; ko += KK) {
        constexpr int NF4 = MT * KK / 4;
        for (int idx = t; idx < NF4; idx += TPB) {
            int m = idx >> 3;
            int jk = idx & 7;
            float4 v = make_float4(0.f, 0.f, 0.f, 0.f);
            if (m0 + m < M)
                v = *(const float4*)&A[(size_t)(m0 + m) * K + ko + jk * 4];
            if (RELU) {
                v.x = fmaxf(v.x, 0.f); v.y = fmaxf(v.y, 0.f);
                v.z = fmaxf(v.z, 0.f); v.w = fmaxf(v.w, 0.f);
            }
            xs[jk * 4 + 0][m] = v.x;
            xs[jk * 4 + 1][m] = v.y;
            xs[jk * 4 + 2][m] = v.z;
            xs[jk * 4 + 3][m] = v.w;
        }
        constexpr int WF4 = KK * NCOL / 4;
        const float4* Wp = (const float4*)(W + (size_t)ko * NCOL);
        float4* wsp = (float4*)&ws[0][0];
        for (int idx = t; idx < WF4; idx += TPB) wsp[idx] = Wp[idx];
        __syncthreads();

#pragma unroll
        for (int kk = 0; kk < KK; kk++) {
            float4 av = *(const float4*)&xs[kk][r0];
            float4 wv = *(const float4*)&ws[kk][c0];
            acc[0][0] += av.x * wv.x; acc[0][1] += av.x * wv.y;
            acc[0][2] += av.x * wv.z; acc[0][3] += av.x * wv.w;
            acc[1][0] += av.y * wv.x; acc[1][1] += av.y * wv.y;
            acc[1][2] += av.y * wv.z; acc[1][3] += av.y * wv.w;
            acc[2][0] += av.z * wv.x; acc[2][1] += av.z * wv.y;
            acc[2][2] += av.z * wv.z; acc[2][3] += av.z * wv.w;
            acc[3][0] += av.w * wv.x; acc[3][1] += av.w * wv.y;
            acc[3][2] += av.w * wv.z; acc[3][3] += av.w * wv.w;
        }
        __syncthreads();
    }

    float4 b4 = make_float4(0.f, 0.f, 0.f, 0.f);
    if (BIAS) b4 = *(const float4*)&bias[c0];
#pragma unroll
    for (int i = 0; i < 4; i++) {
        int row = m0 + r0 + i;
        if (row < M) {
            float4 o;
            o.x = acc[i][0] + b4.x; o.y = acc[i][1] + b4.y;
            o.z = acc[i][2] + b4.z; o.w = acc[i][3] + b4.w;
            *(float4*)&C[(size_t)row * NCOL + c0] = o;
        }
    }
}

// ---------------------------------------------------------------------------
// CSR gather aggregation: agg[n][c] = hW[n][c]*dinv[n]^2 + b[c]
//                                   + sum_{s in in(n)} hW[s][c]*dinv[s]*dinv[n]
template <int NC>
__global__ __launch_bounds__(256)
void agg_kernel(const float* __restrict__ hW, const float* __restrict__ dinv,
                const int* __restrict__ rowptr, const int* __restrict__ src_sorted,
                const float* __restrict__ b, float* __restrict__ agg, int N) {
    constexpr int TPN = NC / 4;       // threads per node (float4 each)
    constexpr int NPB = 256 / TPN;    // nodes per block
    const int t = threadIdx.x;
    const int node = blockIdx.x * NPB + t / TPN;
    if (node >= N) return;
    const int c4 = (t % TPN) * 4;

    const float dn = dinv[node];
    float4 h = *(const float4*)&hW[(size_t)node * NC + c4];
    float4 bb = *(const float4*)&b[c4];
    float4 acc;
    acc.x = h.x * dn * dn + bb.x;
    acc.y = h.y * dn * dn + bb.y;
    acc.z = h.z * dn * dn + bb.z;
    acc.w = h.w * dn * dn + bb.w;

    const int i1 = rowptr[node + 1];
    for (int i = rowptr[node]; i < i1; i++) {
        int s = src_sorted[i];
        float w = dinv[s] * dn;
        float4 v = *(const float4*)&hW[(size_t)s * NC + c4];
        acc.x += v.x * w; acc.y += v.y * w; acc.z += v.z * w; acc.w += v.w * w;
    }
    *(float4*)&agg[(size_t)node * NC + c4] = acc;
}

// ---------------------------------------------------------------------------
// Build Wc[64][128] = [W_m0_top | W_m0_bot]
__global__ void concat_w_kernel(const float* __restrict__ Wm0, float* __restrict__ Wc) {
    int i = blockIdx.x * 256 + threadIdx.x;
    if (i < 64 * 128) {
        int k = i >> 7, j = i & 127;
        Wc[i] = (j < 64) ? Wm0[k * 64 + j] : Wm0[(64 + k) * 64 + (j - 64)];
    }
}

// ---------------------------------------------------------------------------
__global__ void stats0_kernel(const float* __restrict__ AB,
                              const int* __restrict__ src,
                              const int* __restrict__ dst,
                              const float* __restrict__ bm0,
                              double* __restrict__ st, int E) {
    int c = threadIdx.x & 63;
    int eg = threadIdx.x >> 6;
    float s1 = 0.f, s2 = 0.f;
    float bm = bm0[c];
    for (int e = blockIdx.x * 4 + eg; e < E; e += gridDim.x * 4) {
        float a = AB[(size_t)src[e] * 128 + c];
        float b = AB[(size_t)dst[e] * 128 + 64 + c];
        float z = a + b + bm;
        s1 += z;
        s2 += z * z;
    }
    __shared__ float r1[256], r2[256];
    r1[threadIdx.x] = s1; r2[threadIdx.x] = s2;
    __syncthreads();
    if (threadIdx.x < 64) {
        float a1 = r1[threadIdx.x] + r1[threadIdx.x + 64] + r1[threadIdx.x + 128] + r1[threadIdx.x + 192];
        float a2 = r2[threadIdx.x] + r2[threadIdx.x + 64] + r2[threadIdx.x + 128] + r2[threadIdx.x + 192];
        atomicAdd(&st[c], (double)a1);
        atomicAdd(&st[64 + c], (double)a2);
    }
}

__global__ void bnprep0_kernel(const double* __restrict__ st,
                               const float* __restrict__ g, const float* __restrict__ be,
                               const float* __restrict__ bm,
                               float* __restrict__ s0, float* __restrict__ t0, int E) {
    int c = threadIdx.x;
    if (c < 64) {
        double mu = st[c] / (double)E;
        double var = st[64 + c] / (double)E - mu * mu;
        double inv = 1.0 / sqrt(var + 1e-5);
        float s = (float)((double)g[c] * inv);
        float t = (float)((double)be[c] - (double)s * mu + (double)s * (double)bm[c]);
        s0[c] = s; t0[c] = t;
    }
}

// ---------------------------------------------------------------------------
__global__ __launch_bounds__(256)
void mlp1_kernel(const float* __restrict__ AB, const int* __restrict__ src,
                 const int* __restrict__ dst, const float* __restrict__ s0,
                 const float* __restrict__ t0, const float* __restrict__ Wm1,
                 const float* __restrict__ bm1, float* __restrict__ z1, int E) {
    int e = blockIdx.x * 256 + threadIdx.x;
    if (e >= E) return;
    const float* Ar = AB + (size_t)src[e] * 128;
    const float* Br = AB + (size_t)dst[e] * 128 + 64;
    float acc[32];
#pragma unroll
    for (int j = 0; j < 32; j++) acc[j] = bm1[j];

    for (int k = 0; k < 64; k += 4) {
        float4 a4 = *(const float4*)&Ar[k];
        float4 b4 = *(const float4*)&Br[k];
        float4 sv = *(const float4*)&s0[k];
        float4 tv = *(const float4*)&t0[k];
        float y0 = fmaxf(sv.x * (a4.x + b4.x) + tv.x, 0.f);
        float y1 = fmaxf(sv.y * (a4.y + b4.y) + tv.y, 0.f);
        float y2 = fmaxf(sv.z * (a4.z + b4.z) + tv.z, 0.f);
        float y3 = fmaxf(sv.w * (a4.w + b4.w) + tv.w, 0.f);
#pragma unroll
        for (int j = 0; j < 32; j++) {
            acc[j] += y0 * Wm1[(k + 0) * 32 + j];
            acc[j] += y1 * Wm1[(k + 1) * 32 + j];
            acc[j] += y2 * Wm1[(k + 2) * 32 + j];
            acc[j] += y3 * Wm1[(k + 3) * 32 + j];
        }
    }
    float4* zp = (float4*)&z1[(size_t)e * 32];
#pragma unroll
    for (int jj = 0; jj < 8; jj++)
        zp[jj] = make_float4(acc[4 * jj], acc[4 * jj + 1], acc[4 * jj + 2], acc[4 * jj + 3]);
}

__global__ void stats1_kernel(const float* __restrict__ z1, double* __restrict__ st, int E) {
    int c = threadIdx.x & 31;
    int eg = threadIdx.x >> 5;
    float s1 = 0.f, s2 = 0.f;
    for (int e = blockIdx.x * 8 + eg; e < E; e += gridDim.x * 8) {
        float z = z1[(size_t)e * 32 + c];
        s1 += z;
        s2 += z * z;
    }
    __shared__ float r1[256], r2[256];
    r1[threadIdx.x] = s1; r2[threadIdx.x] = s2;
    __syncthreads();
    if (threadIdx.x < 32) {
        float a1 = 0.f, a2 = 0.f;
#pragma unroll
        for (int gq = 0; gq < 8; gq++) { a1 += r1[threadIdx.x + 32 * gq]; a2 += r2[threadIdx.x + 32 * gq]; }
        atomicAdd(&st[c], (double)a1);
        atomicAdd(&st[32 + c], (double)a2);
    }
}

__global__ void bnprep1_kernel(const double* __restrict__ st,
                               const float* __restrict__ g, const float* __restrict__ be,
                               float* __restrict__ s1, float* __restrict__ t1, int E) {
    int c = threadIdx.x;
    if (c < 32) {
        double mu = st[c] / (double)E;
        double var = st[32 + c] / (double)E - mu * mu;
        double inv = 1.0 / sqrt(var + 1e-5);
        float s = (float)((double)g[c] * inv);
        float t = (float)((double)be[c] - (double)s * mu);
        s1[c] = s; t1[c] = t;
    }
}

__global__ void mlp2_kernel(const float* __restrict__ z1, const float* __restrict__ s1,
                            const float* __restrict__ t1, const float* __restrict__ Wm2,
                            const float* __restrict__ bm2, float* __restrict__ out, int E) {
    int e = blockIdx.x * 256 + threadIdx.x;
    if (e >= E) return;
    const float* zr = z1 + (size_t)e * 32;
    float acc = bm2[0];
#pragma unroll
    for (int k = 0; k < 32; k += 4) {
        float4 z4 = *(const float4*)&zr[k];
        float4 sv = *(const float4*)&s1[k];
        float4 tv = *(const float4*)&t1[k];
        float4 wv = *(const float4*)&Wm2[k];
        acc += fmaxf(sv.x * z4.x + tv.x, 0.f) * wv.x;
        acc += fmaxf(sv.y * z4.y + tv.y, 0.f) * wv.y;
        acc += fmaxf(sv.z * z4.z + tv.z, 0.f) * wv.z;
        acc += fmaxf(sv.w * z4.w + tv.w, 0.f) * wv.w;
    }
    out[e] = 1.f / (1.f + expf(-acc));
}

// ---------------------------------------------------------------------------
extern "C" void kernel_launch(void* const* d_in, const int* in_sizes, int n_in,
                              void* d_out, int out_size, void* d_ws, size_t ws_size,
                              hipStream_t stream) {
    const float* x      = (const float*)d_in[0];
    const int*   eidx   = (const int*)d_in[1];
    const float* W_emb  = (const float*)d_in[2];
    const float* b_emb  = (const float*)d_in[3];
    const float* W_g1   = (const float*)d_in[4];
    const float* b_g1   = (const float*)d_in[5];
    const float* W_g2   = (const float*)d_in[6];
    const float* b_g2   = (const float*)d_in[7];
    const float* W_m0   = (const float*)d_in[8];
    const float* b_m0   = (const float*)d_in[9];
    const float* g_m0   = (const float*)d_in[10];
    const float* be_m0  = (const float*)d_in[11];
    const float* W_m1   = (const float*)d_in[12];
    const float* b_m1   = (const float*)d_in[13];
    const float* g_m1   = (const float*)d_in[14];
    const float* be_m1  = (const float*)d_in[15];
    const float* W_m2   = (const float*)d_in[16];
    const float* b_m2   = (const float*)d_in[17];
    float* out = (float*)d_out;

    const int N = in_sizes[0] / IN_D;   // 50000
    const int E = in_sizes[1] / 2;      // 800000
    const int* src = eidx;
    const int* dst = eidx + E;

    char* p = (char*)d_ws;
    auto alloc = [&](size_t bytes) {
        void* r = (void*)p;
        p += (bytes + 255) & ~(size_t)255;
        return r;
    };
    int*    hist   = (int*)alloc((size_t)N * 4);
    int*    rowptr = (int*)alloc((size_t)(N + 1) * 4);
    int*    cursor = (int*)alloc((size_t)N * 4);
    int*    ssort  = (int*)alloc((size_t)E * 4);
    float*  dinv   = (float*)alloc((size_t)N * 4);
    float*  B2     = (float*)alloc((size_t)N * HIDD * 4);   // h0, later agg2
    float*  B3     = (float*)alloc((size_t)N * HIDD * 4);   // hW1, later hW2
    float*  B4     = (float*)alloc((size_t)N * HIDD * 4);   // agg1, later AB
    float*  z1     = (float*)alloc((size_t)E * 32 * 4);
    float*  Wc     = (float*)alloc(64 * 128 * 4);
    double* st0    = (double*)alloc(128 * 8);
    double* st1    = (double*)alloc(64 * 8);
    float*  s0     = (float*)alloc(64 * 4);
    float*  t0     = (float*)alloc(64 * 4);
    float*  s1     = (float*)alloc(32 * 4);
    float*  t1     = (float*)alloc(32 * 4);

    float* h0   = B2;  float* agg2 = B2;
    float* hW1  = B3;  float* hW2  = B3;
    float* agg1 = B4;  float* AB   = B4;

    const int nbE = (E + 255) / 256;

    // CSR build (dst-sorted) + dinv
    init_kernel<<<(N + 255) / 256, 256, 0, stream>>>(hist, st0, st1, N);
    hist_kernel<<<nbE, 256, 0, stream>>>(dst, hist, E);
    scan_kernel<<<1, 1024, 0, stream>>>(hist, rowptr, cursor, dinv, N, E);
    fill_kernel<<<nbE, 256, 0, stream>>>(src, dst, cursor, ssort, E);

    // embedding: h0 = x @ W_emb + b_emb
    mm_kernel<256, 128, false, true><<<(N + 63) / 64, 512, 0, stream>>>(x, W_emb, b_emb, h0, N);

    // GCN1: hW1 = h0 @ W_g1; agg1 = sym-norm CSR aggregate + self-loop + bias
    mm_kernel<128, 128, false, false><<<(N + 63) / 64, 512, 0, stream>>>(h0, W_g1, nullptr, hW1, N);
    agg_kernel<128><<<(N + 7) / 8, 256, 0, stream>>>(hW1, dinv, rowptr, ssort, b_g1, agg1, N);

    // GCN2 (relu on agg1 fused into GEMM staging)
    mm_kernel<128, 64, true, false><<<(N + 63) / 64, 256, 0, stream>>>(agg1, W_g2, nullptr, hW2, N);
    agg_kernel<64><<<(N + 15) / 16, 256, 0, stream>>>(hW2, dinv, rowptr, ssort, b_g2, agg2, N);

    // AB = h2 @ [Wtop|Wbot]  (edge MLP layer-0 factorization)
    concat_w_kernel<<<32, 256, 0, stream>>>(W_m0, Wc);
    mm_kernel<64, 128, false, false><<<(N + 63) / 64, 512, 0, stream>>>(agg2, Wc, nullptr, AB, N);

    // BN0 stats -> scale/shift
    stats0_kernel<<<1024, 256, 0, stream>>>(AB, src, dst, b_m0, st0, E);
    bnprep0_kernel<<<1, 64, 0, stream>>>(st0, g_m0, be_m0, b_m0, s0, t0, E);

    // MLP1 -> z1, BN1 stats -> scale/shift
    mlp1_kernel<<<nbE, 256, 0, stream>>>(AB, src, dst, s0, t0, W_m1, b_m1, z1, E);
    stats1_kernel<<<1024, 256, 0, stream>>>(z1, st1, E);
    bnprep1_kernel<<<1, 32, 0, stream>>>(st1, g_m1, be_m1, s1, t1, E);

    // MLP2 + sigmoid
    mlp2_kernel<<<nbE, 256, 0, stream>>>(z1, s1, t1, W_m2, b_m2, out, E);
}

// Round 5
// 815.013 us; speedup vs baseline: 1.6024x; 1.2878x over previous
//
#include <hip/hip_runtime.h>
#include <math.h>

static constexpr int IN_D = 256;
static constexpr int HIDD = 128;

// ---------------------------------------------------------------------------
__global__ void init_kernel(int* __restrict__ hist, double* __restrict__ st0,
                            double* __restrict__ st1, int n) {
    int i = blockIdx.x * 256 + threadIdx.x;
    if (i < n) hist[i] = 0;
    if (i < 128) st0[i] = 0.0;
    if (i < 64)  st1[i] = 0.0;
}

__global__ void hist_kernel(const int* __restrict__ dst, int* __restrict__ hist, int E) {
    int e = blockIdx.x * 256 + threadIdx.x;
    if (e < E) atomicAdd(&hist[dst[e]], 1);
}

// Single-block exclusive scan over hist[N] -> rowptr/cursor; dinv = rsqrt(deg+1)
__global__ __launch_bounds__(1024)
void scan_kernel(const int* __restrict__ hist, int* __restrict__ rowptr,
                 int* __restrict__ cursor, float* __restrict__ dinv, int N, int E) {
    __shared__ int lsum[1024];
    const int t = threadIdx.x;
    const int chunk = (N + 1023) >> 10;
    const int lo = t * chunk;
    const int hi = min(N, lo + chunk);
    int s = 0;
    for (int i = lo; i < hi; i++) s += hist[i];
    lsum[t] = s;
    __syncthreads();
    for (int off = 1; off < 1024; off <<= 1) {
        int v = (t >= off) ? lsum[t - off] : 0;
        __syncthreads();
        lsum[t] += v;
        __syncthreads();
    }
    int run = lsum[t] - s;  // exclusive prefix
    for (int i = lo; i < hi; i++) {
        rowptr[i] = run;
        cursor[i] = run;
        dinv[i] = rsqrtf((float)hist[i] + 1.0f);  // +1 self-loop
        run += hist[i];
    }
    if (t == 1023) rowptr[N] = E;
}

__global__ void fill_kernel(const int* __restrict__ src, const int* __restrict__ dst,
                            int* __restrict__ cursor, int* __restrict__ ssort,
                            int* __restrict__ dsort, int* __restrict__ esort, int E) {
    int e = blockIdx.x * 256 + threadIdx.x;
    if (e < E) {
        int d = dst[e];
        int pos = atomicAdd(&cursor[d], 1);
        ssort[pos] = src[e];
        dsort[pos] = d;
        esort[pos] = e;
    }
}

// ---------------------------------------------------------------------------
// Generic tiled f32 GEMM: C[M,NCOL] = op(A[M,K]) @ W[K,NCOL] (+ bias)
template <int K, int NCOL, bool RELU, bool BIAS>
__global__ __launch_bounds__((NCOL / 4) * 16)
void mm_kernel(const float* __restrict__ A, const float* __restrict__ W,
               const float* __restrict__ bias, float* __restrict__ C, int M) {
    constexpr int MT = 64;
    constexpr int KK = 32;
    constexpr int TPB = (NCOL / 4) * (MT / 4);
    __shared__ float xs[KK][MT + 4];
    __shared__ float ws[KK][NCOL];

    const int t = threadIdx.x;
    const int m0 = blockIdx.x * MT;
    const int tc = t % (NCOL / 4);
    const int tr = t / (NCOL / 4);
    const int c0 = tc * 4, r0 = tr * 4;

    float acc[4][4] = {};

    for (int ko = 0; ko < K; ko += KK) {
        constexpr int NF4 = MT * KK / 4;
        for (int idx = t; idx < NF4; idx += TPB) {
            int m = idx >> 3;
            int jk = idx & 7;
            float4 v = make_float4(0.f, 0.f, 0.f, 0.f);
            if (m0 + m < M)
                v = *(const float4*)&A[(size_t)(m0 + m) * K + ko + jk * 4];
            if (RELU) {
                v.x = fmaxf(v.x, 0.f); v.y = fmaxf(v.y, 0.f);
                v.z = fmaxf(v.z, 0.f); v.w = fmaxf(v.w, 0.f);
            }
            xs[jk * 4 + 0][m] = v.x;
            xs[jk * 4 + 1][m] = v.y;
            xs[jk * 4 + 2][m] = v.z;
            xs[jk * 4 + 3][m] = v.w;
        }
        constexpr int WF4 = KK * NCOL / 4;
        const float4* Wp = (const float4*)(W + (size_t)ko * NCOL);
        float4* wsp = (float4*)&ws[0][0];
        for (int idx = t; idx < WF4; idx += TPB) wsp[idx] = Wp[idx];
        __syncthreads();

#pragma unroll
        for (int kk = 0; kk < KK; kk++) {
            float4 av = *(const float4*)&xs[kk][r0];
            float4 wv = *(const float4*)&ws[kk][c0];
            acc[0][0] += av.x * wv.x; acc[0][1] += av.x * wv.y;
            acc[0][2] += av.x * wv.z; acc[0][3] += av.x * wv.w;
            acc[1][0] += av.y * wv.x; acc[1][1] += av.y * wv.y;
            acc[1][2] += av.y * wv.z; acc[1][3] += av.y * wv.w;
            acc[2][0] += av.z * wv.x; acc[2][1] += av.z * wv.y;
            acc[2][2] += av.z * wv.z; acc[2][3] += av.z * wv.w;
            acc[3][0] += av.w * wv.x; acc[3][1] += av.w * wv.y;
            acc[3][2] += av.w * wv.z; acc[3][3] += av.w * wv.w;
        }
        __syncthreads();
    }

    float4 b4 = make_float4(0.f, 0.f, 0.f, 0.f);
    if (BIAS) b4 = *(const float4*)&bias[c0];
#pragma unroll
    for (int i = 0; i < 4; i++) {
        int row = m0 + r0 + i;
        if (row < M) {
            float4 o;
            o.x = acc[i][0] + b4.x; o.y = acc[i][1] + b4.y;
            o.z = acc[i][2] + b4.z; o.w = acc[i][3] + b4.w;
            *(float4*)&C[(size_t)row * NCOL + c0] = o;
        }
    }
}

// ---------------------------------------------------------------------------
// CSR gather aggregation: agg[n][c] = hW[n][c]*dinv[n]^2 + b[c]
//                                   + sum_{s in in(n)} hW[s][c]*dinv[s]*dinv[n]
template <int NC>
__global__ __launch_bounds__(256)
void agg_kernel(const float* __restrict__ hW, const float* __restrict__ dinv,
                const int* __restrict__ rowptr, const int* __restrict__ src_sorted,
                const float* __restrict__ b, float* __restrict__ agg, int N) {
    constexpr int TPN = NC / 4;
    constexpr int NPB = 256 / TPN;
    const int t = threadIdx.x;
    const int node = blockIdx.x * NPB + t / TPN;
    if (node >= N) return;
    const int c4 = (t % TPN) * 4;

    const float dn = dinv[node];
    float4 h = *(const float4*)&hW[(size_t)node * NC + c4];
    float4 bb = *(const float4*)&b[c4];
    float4 acc;
    acc.x = h.x * dn * dn + bb.x;
    acc.y = h.y * dn * dn + bb.y;
    acc.z = h.z * dn * dn + bb.z;
    acc.w = h.w * dn * dn + bb.w;

    const int i1 = rowptr[node + 1];
    for (int i = rowptr[node]; i < i1; i++) {
        int s = src_sorted[i];
        float w = dinv[s] * dn;
        float4 v = *(const float4*)&hW[(size_t)s * NC + c4];
        acc.x += v.x * w; acc.y += v.y * w; acc.z += v.z * w; acc.w += v.w * w;
    }
    *(float4*)&agg[(size_t)node * NC + c4] = acc;
}

// ---------------------------------------------------------------------------
// Build Wc[64][128] = [W_m0_top | W_m0_bot]
__global__ void concat_w_kernel(const float* __restrict__ Wm0, float* __restrict__ Wc) {
    int i = blockIdx.x * 256 + threadIdx.x;
    if (i < 64 * 128) {
        int k = i >> 7, j = i & 127;
        Wc[i] = (j < 64) ? Wm0[k * 64 + j] : Wm0[(64 + k) * 64 + (j - 64)];
    }
}

// ---------------------------------------------------------------------------
// z0 producer + BN0 stats, dst-sorted block-contiguous order.
// z0[pos][c] = A[ssort[pos]][c] + B[dsort[pos]][c] + bm0[c]   (B = cols 64..127)
// STORE: also write z0 to global (consumed by mlp1_stream).
template <bool STORE>
__global__ __launch_bounds__(256)
void z0stats_kernel(const float* __restrict__ AB, const int* __restrict__ ssort,
                    const int* __restrict__ dsort, const float* __restrict__ bm0,
                    float* __restrict__ z0, double* __restrict__ st, int E, int EB) {
    const int t = threadIdx.x;
    const int c4 = (t & 15) * 4;
    const int sub = t >> 4;          // 16 edge slots per block iteration
    const int base = blockIdx.x * EB;
    const int end = min(E, base + EB);
    float4 bm = *(const float4*)&bm0[c4];
    float s1x = 0, s1y = 0, s1z = 0, s1w = 0;
    float s2x = 0, s2y = 0, s2z = 0, s2w = 0;

    for (int pos = base + sub; pos < end; pos += 16) {
        int s = ssort[pos], d = dsort[pos];
        float4 a = *(const float4*)&AB[(size_t)s * 128 + c4];
        float4 b = *(const float4*)&AB[(size_t)d * 128 + 64 + c4];
        float4 z;
        z.x = a.x + b.x + bm.x;
        z.y = a.y + b.y + bm.y;
        z.z = a.z + b.z + bm.z;
        z.w = a.w + b.w + bm.w;
        if (STORE) *(float4*)&z0[(size_t)pos * 64 + c4] = z;
        s1x += z.x; s1y += z.y; s1z += z.z; s1w += z.w;
        s2x += z.x * z.x; s2y += z.y * z.y; s2z += z.z * z.z; s2w += z.w * z.w;
    }

    __shared__ float r1[16][64], r2[16][64];
    r1[sub][c4 + 0] = s1x; r1[sub][c4 + 1] = s1y; r1[sub][c4 + 2] = s1z; r1[sub][c4 + 3] = s1w;
    r2[sub][c4 + 0] = s2x; r2[sub][c4 + 1] = s2y; r2[sub][c4 + 2] = s2z; r2[sub][c4 + 3] = s2w;
    __syncthreads();
    if (t < 64) {
        float a1 = 0.f, a2 = 0.f;
#pragma unroll
        for (int q = 0; q < 16; q++) { a1 += r1[q][t]; a2 += r2[q][t]; }
        atomicAdd(&st[t], (double)a1);
        atomicAdd(&st[64 + t], (double)a2);
    }
}

// z0 already includes b_m0, so: s = g*rsqrt(var+eps), t = be - s*mu
__global__ void bnprep0_kernel(const double* __restrict__ st,
                               const float* __restrict__ g, const float* __restrict__ be,
                               float* __restrict__ s0, float* __restrict__ t0, int E) {
    int c = threadIdx.x;
    if (c < 64) {
        double mu = st[c] / (double)E;
        double var = st[64 + c] / (double)E - mu * mu;
        double inv = 1.0 / sqrt(var + 1e-5);
        float s = (float)((double)g[c] * inv);
        float t = (float)((double)be[c] - (double)s * mu);
        s0[c] = s; t0[c] = t;
    }
}

// ---------------------------------------------------------------------------
// MLP layer 1, streaming variant: read z0[pos], BN0+ReLU, @W_m1 -> z1[pos]
__global__ __launch_bounds__(256)
void mlp1_stream_kernel(const float* __restrict__ z0, const float* __restrict__ s0v,
                        const float* __restrict__ t0v, const float* __restrict__ Wm1,
                        const float* __restrict__ bm1, float* __restrict__ z1, int E) {
    __shared__ float wls[64 * 32];
    __shared__ float sls[64], tls[64], bls[32];
    for (int i = threadIdx.x; i < 2048; i += 256) wls[i] = Wm1[i];
    if (threadIdx.x < 64) { sls[threadIdx.x] = s0v[threadIdx.x]; tls[threadIdx.x] = t0v[threadIdx.x]; }
    if (threadIdx.x < 32) bls[threadIdx.x] = bm1[threadIdx.x];
    __syncthreads();

    int pos = blockIdx.x * 256 + threadIdx.x;
    if (pos >= E) return;
    const float* zr = &z0[(size_t)pos * 64];
    float acc[32];
#pragma unroll
    for (int j = 0; j < 32; j++) acc[j] = bls[j];
#pragma unroll
    for (int k = 0; k < 64; k += 4) {
        float4 z4 = *(const float4*)&zr[k];
        float4 sv = *(const float4*)&sls[k];
        float4 tv = *(const float4*)&tls[k];
        float y0 = fmaxf(sv.x * z4.x + tv.x, 0.f);
        float y1 = fmaxf(sv.y * z4.y + tv.y, 0.f);
        float y2 = fmaxf(sv.z * z4.z + tv.z, 0.f);
        float y3 = fmaxf(sv.w * z4.w + tv.w, 0.f);
#pragma unroll
        for (int j = 0; j < 32; j++) {
            acc[j] += y0 * wls[(k + 0) * 32 + j] + y1 * wls[(k + 1) * 32 + j]
                    + y2 * wls[(k + 2) * 32 + j] + y3 * wls[(k + 3) * 32 + j];
        }
    }
    float4* zp = (float4*)&z1[(size_t)pos * 32];
#pragma unroll
    for (int jj = 0; jj < 8; jj++)
        zp[jj] = make_float4(acc[4 * jj], acc[4 * jj + 1], acc[4 * jj + 2], acc[4 * jj + 3]);
}

// MLP layer 1, gather fallback (ws too small for z0): sorted-order gather from AB
__global__ __launch_bounds__(256)
void mlp1_gather_kernel(const float* __restrict__ AB, const int* __restrict__ ssort,
                        const int* __restrict__ dsort, const float* __restrict__ bm0,
                        const float* __restrict__ s0v, const float* __restrict__ t0v,
                        const float* __restrict__ Wm1, const float* __restrict__ bm1,
                        float* __restrict__ z1, int E) {
    __shared__ float wls[64 * 32];
    __shared__ float sls[64], tls[64], mls[64], bls[32];
    for (int i = threadIdx.x; i < 2048; i += 256) wls[i] = Wm1[i];
    if (threadIdx.x < 64) {
        sls[threadIdx.x] = s0v[threadIdx.x];
        tls[threadIdx.x] = t0v[threadIdx.x];
        mls[threadIdx.x] = bm0[threadIdx.x];
    }
    if (threadIdx.x < 32) bls[threadIdx.x] = bm1[threadIdx.x];
    __syncthreads();

    int pos = blockIdx.x * 256 + threadIdx.x;
    if (pos >= E) return;
    const float* Ar = AB + (size_t)ssort[pos] * 128;
    const float* Br = AB + (size_t)dsort[pos] * 128 + 64;
    float acc[32];
#pragma unroll
    for (int j = 0; j < 32; j++) acc[j] = bls[j];
#pragma unroll
    for (int k = 0; k < 64; k += 4) {
        float4 a4 = *(const float4*)&Ar[k];
        float4 b4 = *(const float4*)&Br[k];
        float4 mv = *(const float4*)&mls[k];
        float4 sv = *(const float4*)&sls[k];
        float4 tv = *(const float4*)&tls[k];
        float y0 = fmaxf(sv.x * (a4.x + b4.x + mv.x) + tv.x, 0.f);
        float y1 = fmaxf(sv.y * (a4.y + b4.y + mv.y) + tv.y, 0.f);
        float y2 = fmaxf(sv.z * (a4.z + b4.z + mv.z) + tv.z, 0.f);
        float y3 = fmaxf(sv.w * (a4.w + b4.w + mv.w) + tv.w, 0.f);
#pragma unroll
        for (int j = 0; j < 32; j++) {
            acc[j] += y0 * wls[(k + 0) * 32 + j] + y1 * wls[(k + 1) * 32 + j]
                    + y2 * wls[(k + 2) * 32 + j] + y3 * wls[(k + 3) * 32 + j];
        }
    }
    float4* zp = (float4*)&z1[(size_t)pos * 32];
#pragma unroll
    for (int jj = 0; jj < 8; jj++)
        zp[jj] = make_float4(acc[4 * jj], acc[4 * jj + 1], acc[4 * jj + 2], acc[4 * jj + 3]);
}

// ---------------------------------------------------------------------------
__global__ void stats1_kernel(const float* __restrict__ z1, double* __restrict__ st, int E) {
    int c = threadIdx.x & 31;
    int eg = threadIdx.x >> 5;
    float s1 = 0.f, s2 = 0.f;
    for (int e = blockIdx.x * 8 + eg; e < E; e += gridDim.x * 8) {
        float z = z1[(size_t)e * 32 + c];
        s1 += z;
        s2 += z * z;
    }
    __shared__ float r1[256], r2[256];
    r1[threadIdx.x] = s1; r2[threadIdx.x] = s2;
    __syncthreads();
    if (threadIdx.x < 32) {
        float a1 = 0.f, a2 = 0.f;
#pragma unroll
        for (int gq = 0; gq < 8; gq++) { a1 += r1[threadIdx.x + 32 * gq]; a2 += r2[threadIdx.x + 32 * gq]; }
        atomicAdd(&st[c], (double)a1);
        atomicAdd(&st[32 + c], (double)a2);
    }
}

__global__ void bnprep1_kernel(const double* __restrict__ st,
                               const float* __restrict__ g, const float* __restrict__ be,
                               float* __restrict__ s1, float* __restrict__ t1, int E) {
    int c = threadIdx.x;
    if (c < 32) {
        double mu = st[c] / (double)E;
        double var = st[32 + c] / (double)E - mu * mu;
        double inv = 1.0 / sqrt(var + 1e-5);
        float s = (float)((double)g[c] * inv);
        float t = (float)((double)be[c] - (double)s * mu);
        s1[c] = s; t1[c] = t;
    }
}

// MLP layer 2 + sigmoid; z1 is in sorted order -> scatter out via esort
__global__ void mlp2_kernel(const float* __restrict__ z1, const int* __restrict__ esort,
                            const float* __restrict__ s1, const float* __restrict__ t1,
                            const float* __restrict__ Wm2, const float* __restrict__ bm2,
                            float* __restrict__ out, int E) {
    int pos = blockIdx.x * 256 + threadIdx.x;
    if (pos >= E) return;
    const float* zr = z1 + (size_t)pos * 32;
    float acc = bm2[0];
#pragma unroll
    for (int k = 0; k < 32; k += 4) {
        float4 z4 = *(const float4*)&zr[k];
        float4 sv = *(const float4*)&s1[k];
        float4 tv = *(const float4*)&t1[k];
        float4 wv = *(const float4*)&Wm2[k];
        acc += fmaxf(sv.x * z4.x + tv.x, 0.f) * wv.x;
        acc += fmaxf(sv.y * z4.y + tv.y, 0.f) * wv.y;
        acc += fmaxf(sv.z * z4.z + tv.z, 0.f) * wv.z;
        acc += fmaxf(sv.w * z4.w + tv.w, 0.f) * wv.w;
    }
    out[esort[pos]] = 1.f / (1.f + expf(-acc));
}

// ---------------------------------------------------------------------------
extern "C" void kernel_launch(void* const* d_in, const int* in_sizes, int n_in,
                              void* d_out, int out_size, void* d_ws, size_t ws_size,
                              hipStream_t stream) {
    const float* x      = (const float*)d_in[0];
    const int*   eidx   = (const int*)d_in[1];
    const float* W_emb  = (const float*)d_in[2];
    const float* b_emb  = (const float*)d_in[3];
    const float* W_g1   = (const float*)d_in[4];
    const float* b_g1   = (const float*)d_in[5];
    const float* W_g2   = (const float*)d_in[6];
    const float* b_g2   = (const float*)d_in[7];
    const float* W_m0   = (const float*)d_in[8];
    const float* b_m0   = (const float*)d_in[9];
    const float* g_m0   = (const float*)d_in[10];
    const float* be_m0  = (const float*)d_in[11];
    const float* W_m1   = (const float*)d_in[12];
    const float* b_m1   = (const float*)d_in[13];
    const float* g_m1   = (const float*)d_in[14];
    const float* be_m1  = (const float*)d_in[15];
    const float* W_m2   = (const float*)d_in[16];
    const float* b_m2   = (const float*)d_in[17];
    float* out = (float*)d_out;

    const int N = in_sizes[0] / IN_D;   // 50000
    const int E = in_sizes[1] / 2;      // 800000
    const int* src = eidx;
    const int* dst = eidx + E;

    char* p = (char*)d_ws;
    auto alloc = [&](size_t bytes) {
        void* r = (void*)p;
        p += (bytes + 255) & ~(size_t)255;
        return r;
    };
    int*    hist   = (int*)alloc((size_t)N * 4);
    int*    rowptr = (int*)alloc((size_t)(N + 1) * 4);
    int*    cursor = (int*)alloc((size_t)N * 4);
    int*    ssort  = (int*)alloc((size_t)E * 4);
    int*    dsort  = (int*)alloc((size_t)E * 4);
    int*    esort  = (int*)alloc((size_t)E * 4);
    float*  dinv   = (float*)alloc((size_t)N * 4);
    float*  B2     = (float*)alloc((size_t)N * HIDD * 4);   // h0, later agg2
    float*  B3     = (float*)alloc((size_t)N * HIDD * 4);   // hW1, later hW2
    float*  B4     = (float*)alloc((size_t)N * HIDD * 4);   // agg1, later AB
    float*  z1     = (float*)alloc((size_t)E * 32 * 4);
    float*  Wc     = (float*)alloc(64 * 128 * 4);
    double* st0    = (double*)alloc(128 * 8);
    double* st1    = (double*)alloc(64 * 8);
    float*  s0     = (float*)alloc(64 * 4);
    float*  t0     = (float*)alloc(64 * 4);
    float*  s1v    = (float*)alloc(32 * 4);
    float*  t1v    = (float*)alloc(32 * 4);

    // z0 (205 MB) only if workspace allows; else gather-fallback path
    size_t used = (size_t)(p - (char*)d_ws);
    size_t z0_bytes = (size_t)E * 64 * 4;
    bool store_z0 = (used + z0_bytes + 256 <= ws_size);
    float* z0 = store_z0 ? (float*)alloc(z0_bytes) : nullptr;

    float* h0   = B2;  float* agg2 = B2;
    float* hW1  = B3;  float* hW2  = B3;
    float* agg1 = B4;  float* AB   = B4;

    const int nbE = (E + 255) / 256;

    // CSR build (dst-sorted) + dinv
    init_kernel<<<(N + 255) / 256, 256, 0, stream>>>(hist, st0, st1, N);
    hist_kernel<<<nbE, 256, 0, stream>>>(dst, hist, E);
    scan_kernel<<<1, 1024, 0, stream>>>(hist, rowptr, cursor, dinv, N, E);
    fill_kernel<<<nbE, 256, 0, stream>>>(src, dst, cursor, ssort, dsort, esort, E);

    // embedding: h0 = x @ W_emb + b_emb
    mm_kernel<256, 128, false, true><<<(N + 63) / 64, 512, 0, stream>>>(x, W_emb, b_emb, h0, N);

    // GCN1
    mm_kernel<128, 128, false, false><<<(N + 63) / 64, 512, 0, stream>>>(h0, W_g1, nullptr, hW1, N);
    agg_kernel<128><<<(N + 7) / 8, 256, 0, stream>>>(hW1, dinv, rowptr, ssort, b_g1, agg1, N);

    // GCN2 (relu on agg1 fused into GEMM staging)
    mm_kernel<128, 64, true, false><<<(N + 63) / 64, 256, 0, stream>>>(agg1, W_g2, nullptr, hW2, N);
    agg_kernel<64><<<(N + 15) / 16, 256, 0, stream>>>(hW2, dinv, rowptr, ssort, b_g2, agg2, N);

    // AB = h2 @ [Wtop|Wbot]  (edge MLP layer-0 factorization)
    concat_w_kernel<<<32, 256, 0, stream>>>(W_m0, Wc);
    mm_kernel<64, 128, false, false><<<(N + 63) / 64, 512, 0, stream>>>(agg2, Wc, nullptr, AB, N);

    // z0 + BN0 stats (dst-sorted, block-contiguous -> B side caches)
    {
        const int NB = 1024;
        int EB = (E + NB - 1) / NB;
        EB = (EB + 15) & ~15;
        if (store_z0)
            z0stats_kernel<true><<<NB, 256, 0, stream>>>(AB, ssort, dsort, b_m0, z0, st0, E, EB);
        else
            z0stats_kernel<false><<<NB, 256, 0, stream>>>(AB, ssort, dsort, b_m0, nullptr, st0, E, EB);
    }
    bnprep0_kernel<<<1, 64, 0, stream>>>(st0, g_m0, be_m0, s0, t0, E);

    // MLP1 -> z1 (sorted order)
    if (store_z0)
        mlp1_stream_kernel<<<nbE, 256, 0, stream>>>(z0, s0, t0, W_m1, b_m1, z1, E);
    else
        mlp1_gather_kernel<<<nbE, 256, 0, stream>>>(AB, ssort, dsort, b_m0, s0, t0, W_m1, b_m1, z1, E);

    // BN1 stats -> scale/shift
    stats1_kernel<<<1024, 256, 0, stream>>>(z1, st1, E);
    bnprep1_kernel<<<1, 32, 0, stream>>>(st1, g_m1, be_m1, s1v, t1v, E);

    // MLP2 + sigmoid, scatter to original edge order
    mlp2_kernel<<<nbE, 256, 0, stream>>>(z1, esort, s1v, t1v, W_m2, b_m2, out, E);
}

// Round 6
// 792.417 us; speedup vs baseline: 1.6481x; 1.0285x over previous
//
#include <hip/hip_runtime.h>
#include <math.h>

static constexpr int IN_D = 256;
static constexpr int HIDD = 128;

// ---------------------------------------------------------------------------
__global__ void init_kernel(int* __restrict__ hist, double* __restrict__ st0,
                            double* __restrict__ st1, int n) {
    int i = blockIdx.x * 256 + threadIdx.x;
    if (i < n) hist[i] = 0;
    if (i < 128) st0[i] = 0.0;
    if (i < 64)  st1[i] = 0.0;
}

__global__ void hist_kernel(const int* __restrict__ dst, int* __restrict__ hist, int E) {
    int e = blockIdx.x * 256 + threadIdx.x;
    if (e < E) atomicAdd(&hist[dst[e]], 1);
}

// Single-block exclusive scan over hist[N] -> rowptr/cursor; dinv = rsqrt(deg+1)
__global__ __launch_bounds__(1024)
void scan_kernel(const int* __restrict__ hist, int* __restrict__ rowptr,
                 int* __restrict__ cursor, float* __restrict__ dinv, int N, int E) {
    __shared__ int lsum[1024];
    const int t = threadIdx.x;
    const int chunk = (N + 1023) >> 10;
    const int lo = t * chunk;
    const int hi = min(N, lo + chunk);
    int s = 0;
    for (int i = lo; i < hi; i++) s += hist[i];
    lsum[t] = s;
    __syncthreads();
    for (int off = 1; off < 1024; off <<= 1) {
        int v = (t >= off) ? lsum[t - off] : 0;
        __syncthreads();
        lsum[t] += v;
        __syncthreads();
    }
    int run = lsum[t] - s;  // exclusive prefix
    for (int i = lo; i < hi; i++) {
        rowptr[i] = run;
        cursor[i] = run;
        dinv[i] = rsqrtf((float)hist[i] + 1.0f);  // +1 self-loop
        run += hist[i];
    }
    if (t == 1023) rowptr[N] = E;
}

__global__ void fill_kernel(const int* __restrict__ src, const int* __restrict__ dst,
                            int* __restrict__ cursor, int* __restrict__ ssort,
                            int* __restrict__ dsort, int* __restrict__ esort, int E) {
    int e = blockIdx.x * 256 + threadIdx.x;
    if (e < E) {
        int d = dst[e];
        int pos = atomicAdd(&cursor[d], 1);
        ssort[pos] = src[e];
        dsort[pos] = d;
        esort[pos] = e;
    }
}

// ---------------------------------------------------------------------------
// Generic tiled f32 GEMM: C[M,NCOL] = op(A[M,K]) @ W[K,NCOL] (+ bias)
template <int K, int NCOL, bool RELU, bool BIAS>
__global__ __launch_bounds__((NCOL / 4) * 16)
void mm_kernel(const float* __restrict__ A, const float* __restrict__ W,
               const float* __restrict__ bias, float* __restrict__ C, int M) {
    constexpr int MT = 64;
    constexpr int KK = 32;
    constexpr int TPB = (NCOL / 4) * (MT / 4);
    __shared__ float xs[KK][MT + 4];
    __shared__ float ws[KK][NCOL];

    const int t = threadIdx.x;
    const int m0 = blockIdx.x * MT;
    const int tc = t % (NCOL / 4);
    const int tr = t / (NCOL / 4);
    const int c0 = tc * 4, r0 = tr * 4;

    float acc[4][4] = {};

    for (int ko = 0; ko < K; ko += KK) {
        constexpr int NF4 = MT * KK / 4;
        for (int idx = t; idx < NF4; idx += TPB) {
            int m = idx >> 3;
            int jk = idx & 7;
            float4 v = make_float4(0.f, 0.f, 0.f, 0.f);
            if (m0 + m < M)
                v = *(const float4*)&A[(size_t)(m0 + m) * K + ko + jk * 4];
            if (RELU) {
                v.x = fmaxf(v.x, 0.f); v.y = fmaxf(v.y, 0.f);
                v.z = fmaxf(v.z, 0.f); v.w = fmaxf(v.w, 0.f);
            }
            xs[jk * 4 + 0][m] = v.x;
            xs[jk * 4 + 1][m] = v.y;
            xs[jk * 4 + 2][m] = v.z;
            xs[jk * 4 + 3][m] = v.w;
        }
        constexpr int WF4 = KK * NCOL / 4;
        const float4* Wp = (const float4*)(W + (size_t)ko * NCOL);
        float4* wsp = (float4*)&ws[0][0];
        for (int idx = t; idx < WF4; idx += TPB) wsp[idx] = Wp[idx];
        __syncthreads();

#pragma unroll
        for (int kk = 0; kk < KK; kk++) {
            float4 av = *(const float4*)&xs[kk][r0];
            float4 wv = *(const float4*)&ws[kk][c0];
            acc[0][0] += av.x * wv.x; acc[0][1] += av.x * wv.y;
            acc[0][2] += av.x * wv.z; acc[0][3] += av.x * wv.w;
            acc[1][0] += av.y * wv.x; acc[1][1] += av.y * wv.y;
            acc[1][2] += av.y * wv.z; acc[1][3] += av.y * wv.w;
            acc[2][0] += av.z * wv.x; acc[2][1] += av.z * wv.y;
            acc[2][2] += av.z * wv.z; acc[2][3] += av.z * wv.w;
            acc[3][0] += av.w * wv.x; acc[3][1] += av.w * wv.y;
            acc[3][2] += av.w * wv.z; acc[3][3] += av.w * wv.w;
        }
        __syncthreads();
    }

    float4 b4 = make_float4(0.f, 0.f, 0.f, 0.f);
    if (BIAS) b4 = *(const float4*)&bias[c0];
#pragma unroll
    for (int i = 0; i < 4; i++) {
        int row = m0 + r0 + i;
        if (row < M) {
            float4 o;
            o.x = acc[i][0] + b4.x; o.y = acc[i][1] + b4.y;
            o.z = acc[i][2] + b4.z; o.w = acc[i][3] + b4.w;
            *(float4*)&C[(size_t)row * NCOL + c0] = o;
        }
    }
}

// ---------------------------------------------------------------------------
// CSR gather aggregation: agg[n][c] = hW[n][c]*dinv[n]^2 + b[c]
//                                   + sum_{s in in(n)} hW[s][c]*dinv[s]*dinv[n]
template <int NC>
__global__ __launch_bounds__(256)
void agg_kernel(const float* __restrict__ hW, const float* __restrict__ dinv,
                const int* __restrict__ rowptr, const int* __restrict__ src_sorted,
                const float* __restrict__ b, float* __restrict__ agg, int N) {
    constexpr int TPN = NC / 4;
    constexpr int NPB = 256 / TPN;
    const int t = threadIdx.x;
    const int node = blockIdx.x * NPB + t / TPN;
    if (node >= N) return;
    const int c4 = (t % TPN) * 4;

    const float dn = dinv[node];
    float4 h = *(const float4*)&hW[(size_t)node * NC + c4];
    float4 bb = *(const float4*)&b[c4];
    float4 acc;
    acc.x = h.x * dn * dn + bb.x;
    acc.y = h.y * dn * dn + bb.y;
    acc.z = h.z * dn * dn + bb.z;
    acc.w = h.w * dn * dn + bb.w;

    const int i1 = rowptr[node + 1];
    for (int i = rowptr[node]; i < i1; i++) {
        int s = src_sorted[i];
        float w = dinv[s] * dn;
        float4 v = *(const float4*)&hW[(size_t)s * NC + c4];
        acc.x += v.x * w; acc.y += v.y * w; acc.z += v.z * w; acc.w += v.w * w;
    }
    *(float4*)&agg[(size_t)node * NC + c4] = acc;
}

// ---------------------------------------------------------------------------
// Build Wc[64][128] = [W_m0_top | W_m0_bot]
__global__ void concat_w_kernel(const float* __restrict__ Wm0, float* __restrict__ Wc) {
    int i = blockIdx.x * 256 + threadIdx.x;
    if (i < 64 * 128) {
        int k = i >> 7, j = i & 127;
        Wc[i] = (j < 64) ? Wm0[k * 64 + j] : Wm0[(64 + k) * 64 + (j - 64)];
    }
}

// ---------------------------------------------------------------------------
// BN0 stats pass, dst-sorted block-contiguous order (no z0 store).
// z0[pos][c] = A[ssort[pos]][c] + B[dsort[pos]][c] + bm0[c]   (B = cols 64..127)
__global__ __launch_bounds__(256)
void z0stats_kernel(const float* __restrict__ AB, const int* __restrict__ ssort,
                    const int* __restrict__ dsort, const float* __restrict__ bm0,
                    double* __restrict__ st, int E, int EB) {
    const int t = threadIdx.x;
    const int c4 = (t & 15) * 4;
    const int sub = t >> 4;          // 16 edge slots per block iteration
    const int base = blockIdx.x * EB;
    const int end = min(E, base + EB);
    float4 bm = *(const float4*)&bm0[c4];
    float s1x = 0, s1y = 0, s1z = 0, s1w = 0;
    float s2x = 0, s2y = 0, s2z = 0, s2w = 0;

    for (int pos = base + sub; pos < end; pos += 16) {
        int s = ssort[pos], d = dsort[pos];
        float4 a = *(const float4*)&AB[(size_t)s * 128 + c4];
        float4 b = *(const float4*)&AB[(size_t)d * 128 + 64 + c4];
        float4 z;
        z.x = a.x + b.x + bm.x;
        z.y = a.y + b.y + bm.y;
        z.z = a.z + b.z + bm.z;
        z.w = a.w + b.w + bm.w;
        s1x += z.x; s1y += z.y; s1z += z.z; s1w += z.w;
        s2x += z.x * z.x; s2y += z.y * z.y; s2z += z.z * z.z; s2w += z.w * z.w;
    }

    __shared__ float r1[16][64], r2[16][64];
    r1[sub][c4 + 0] = s1x; r1[sub][c4 + 1] = s1y; r1[sub][c4 + 2] = s1z; r1[sub][c4 + 3] = s1w;
    r2[sub][c4 + 0] = s2x; r2[sub][c4 + 1] = s2y; r2[sub][c4 + 2] = s2z; r2[sub][c4 + 3] = s2w;
    __syncthreads();
    if (t < 64) {
        float a1 = 0.f, a2 = 0.f;
#pragma unroll
        for (int q = 0; q < 16; q++) { a1 += r1[q][t]; a2 += r2[q][t]; }
        atomicAdd(&st[t], (double)a1);
        atomicAdd(&st[64 + t], (double)a2);
    }
}

// z0 already includes b_m0, so: s = g*rsqrt(var+eps), t = be - s*mu
__global__ void bnprep0_kernel(const double* __restrict__ st,
                               const float* __restrict__ g, const float* __restrict__ be,
                               float* __restrict__ s0, float* __restrict__ t0, int E) {
    int c = threadIdx.x;
    if (c < 64) {
        double mu = st[c] / (double)E;
        double var = st[64 + c] / (double)E - mu * mu;
        double inv = 1.0 / sqrt(var + 1e-5);
        float s = (float)((double)g[c] * inv);
        float t = (float)((double)be[c] - (double)s * mu);
        s0[c] = s; t0[c] = t;
    }
}

// ---------------------------------------------------------------------------
// MLP layer 1 as an edge-tile GEMM, with BN1 stats fused.
// Per block: 128 sorted edges. Stage y0 = relu(s0*(A[s]+B[d]+bm0)+t0) transposed
// into LDS, then 4x4-register-tile GEMM vs W_m1 (LDS), z1 out + stats.
__global__ __launch_bounds__(256)
void mlp1_fused_kernel(const float* __restrict__ AB, const int* __restrict__ ssort,
                       const int* __restrict__ dsort, const float* __restrict__ bm0v,
                       const float* __restrict__ s0v, const float* __restrict__ t0v,
                       const float* __restrict__ Wm1, const float* __restrict__ bm1,
                       float* __restrict__ z1, double* __restrict__ st, int E) {
    constexpr int TE = 128;
    __shared__ float yt[64][TE + 4];     // y0 transposed: yt[k][edge]
    __shared__ float wls[64 * 32];
    __shared__ float svls[64], tvls[64], bmls[64], b1ls[32];
    __shared__ float ls1[32][32], ls2[32][32];

    const int t = threadIdx.x;
    for (int i = t; i < 2048; i += 256) wls[i] = Wm1[i];
    if (t < 64) { svls[t] = s0v[t]; tvls[t] = t0v[t]; bmls[t] = bm0v[t]; }
    if (t < 32) b1ls[t] = bm1[t];
    for (int i = t; i < 1024; i += 256) { (&ls1[0][0])[i] = 0.f; (&ls2[0][0])[i] = 0.f; }
    __syncthreads();

    // ---- stage: 2 threads per edge, each covers 32 channels ----
    const int base = blockIdx.x * TE;
    const int le = t >> 1, half = t & 1;
    const int pos = base + le;
    if (pos < E) {
        const int s = ssort[pos], d = dsort[pos];
        const float* Ar = AB + (size_t)s * 128;
        const float* Br = AB + (size_t)d * 128 + 64;
#pragma unroll
        for (int q = 0; q < 8; q++) {
            int c = half * 32 + q * 4;
            float4 a = *(const float4*)&Ar[c];
            float4 b = *(const float4*)&Br[c];
            float4 sv = *(const float4*)&svls[c];
            float4 tv = *(const float4*)&tvls[c];
            float4 mv = *(const float4*)&bmls[c];
            yt[c + 0][le] = fmaxf(sv.x * (a.x + b.x + mv.x) + tv.x, 0.f);
            yt[c + 1][le] = fmaxf(sv.y * (a.y + b.y + mv.y) + tv.y, 0.f);
            yt[c + 2][le] = fmaxf(sv.z * (a.z + b.z + mv.z) + tv.z, 0.f);
            yt[c + 3][le] = fmaxf(sv.w * (a.w + b.w + mv.w) + tv.w, 0.f);
        }
    } else {
#pragma unroll
        for (int q = 0; q < 8; q++) {
            int c = half * 32 + q * 4;
            yt[c + 0][le] = 0.f; yt[c + 1][le] = 0.f;
            yt[c + 2][le] = 0.f; yt[c + 3][le] = 0.f;
        }
    }
    __syncthreads();

    // ---- GEMM: out tile 128 edges x 32 cols, 4x4 per thread ----
    const int tr = t >> 3, tc = t & 7;     // tr 0..31 (edge groups), tc 0..7 (col groups)
    const int r0 = tr * 4, c0 = tc * 4;
    float acc[4][4];
#pragma unroll
    for (int i = 0; i < 4; i++) {
        acc[i][0] = b1ls[c0 + 0]; acc[i][1] = b1ls[c0 + 1];
        acc[i][2] = b1ls[c0 + 2]; acc[i][3] = b1ls[c0 + 3];
    }
#pragma unroll 8
    for (int kk = 0; kk < 64; kk++) {
        float4 av = *(const float4*)&yt[kk][r0];
        float4 wv = *(const float4*)&wls[kk * 32 + c0];
        acc[0][0] += av.x * wv.x; acc[0][1] += av.x * wv.y;
        acc[0][2] += av.x * wv.z; acc[0][3] += av.x * wv.w;
        acc[1][0] += av.y * wv.x; acc[1][1] += av.y * wv.y;
        acc[1][2] += av.y * wv.z; acc[1][3] += av.y * wv.w;
        acc[2][0] += av.z * wv.x; acc[2][1] += av.z * wv.y;
        acc[2][2] += av.z * wv.z; acc[2][3] += av.z * wv.w;
        acc[3][0] += av.w * wv.x; acc[3][1] += av.w * wv.y;
        acc[3][2] += av.w * wv.z; acc[3][3] += av.w * wv.w;
    }

    // ---- z1 write + local BN1 stats ----
    float cs1[4] = {0.f, 0.f, 0.f, 0.f};
    float cs2[4] = {0.f, 0.f, 0.f, 0.f};
#pragma unroll
    for (int i = 0; i < 4; i++) {
        int pz = base + r0 + i;
        if (pz < E) {
            float4 o;
            o.x = acc[i][0]; o.y = acc[i][1]; o.z = acc[i][2]; o.w = acc[i][3];
            *(float4*)&z1[(size_t)pz * 32 + c0] = o;
            cs1[0] += o.x; cs1[1] += o.y; cs1[2] += o.z; cs1[3] += o.w;
            cs2[0] += o.x * o.x; cs2[1] += o.y * o.y;
            cs2[2] += o.z * o.z; cs2[3] += o.w * o.w;
        }
    }
    // unique (tr, c0) slot per thread -> no race
    ls1[tr][c0 + 0] = cs1[0]; ls1[tr][c0 + 1] = cs1[1];
    ls1[tr][c0 + 2] = cs1[2]; ls1[tr][c0 + 3] = cs1[3];
    ls2[tr][c0 + 0] = cs2[0]; ls2[tr][c0 + 1] = cs2[1];
    ls2[tr][c0 + 2] = cs2[2]; ls2[tr][c0 + 3] = cs2[3];
    __syncthreads();
    if (t < 32) {
        float a1 = 0.f, a2 = 0.f;
#pragma unroll
        for (int r = 0; r < 32; r++) { a1 += ls1[r][t]; a2 += ls2[r][t]; }
        atomicAdd(&st[t], (double)a1);
        atomicAdd(&st[32 + t], (double)a2);
    }
}

__global__ void bnprep1_kernel(const double* __restrict__ st,
                               const float* __restrict__ g, const float* __restrict__ be,
                               float* __restrict__ s1, float* __restrict__ t1, int E) {
    int c = threadIdx.x;
    if (c < 32) {
        double mu = st[c] / (double)E;
        double var = st[32 + c] / (double)E - mu * mu;
        double inv = 1.0 / sqrt(var + 1e-5);
        float s = (float)((double)g[c] * inv);
        float t = (float)((double)be[c] - (double)s * mu);
        s1[c] = s; t1[c] = t;
    }
}

// MLP layer 2 + sigmoid; z1 is in sorted order -> scatter out via esort
__global__ void mlp2_kernel(const float* __restrict__ z1, const int* __restrict__ esort,
                            const float* __restrict__ s1, const float* __restrict__ t1,
                            const float* __restrict__ Wm2, const float* __restrict__ bm2,
                            float* __restrict__ out, int E) {
    int pos = blockIdx.x * 256 + threadIdx.x;
    if (pos >= E) return;
    const float* zr = z1 + (size_t)pos * 32;
    float acc = bm2[0];
#pragma unroll
    for (int k = 0; k < 32; k += 4) {
        float4 z4 = *(const float4*)&zr[k];
        float4 sv = *(const float4*)&s1[k];
        float4 tv = *(const float4*)&t1[k];
        float4 wv = *(const float4*)&Wm2[k];
        acc += fmaxf(sv.x * z4.x + tv.x, 0.f) * wv.x;
        acc += fmaxf(sv.y * z4.y + tv.y, 0.f) * wv.y;
        acc += fmaxf(sv.z * z4.z + tv.z, 0.f) * wv.z;
        acc += fmaxf(sv.w * z4.w + tv.w, 0.f) * wv.w;
    }
    out[esort[pos]] = 1.f / (1.f + expf(-acc));
}

// ---------------------------------------------------------------------------
extern "C" void kernel_launch(void* const* d_in, const int* in_sizes, int n_in,
                              void* d_out, int out_size, void* d_ws, size_t ws_size,
                              hipStream_t stream) {
    const float* x      = (const float*)d_in[0];
    const int*   eidx   = (const int*)d_in[1];
    const float* W_emb  = (const float*)d_in[2];
    const float* b_emb  = (const float*)d_in[3];
    const float* W_g1   = (const float*)d_in[4];
    const float* b_g1   = (const float*)d_in[5];
    const float* W_g2   = (const float*)d_in[6];
    const float* b_g2   = (const float*)d_in[7];
    const float* W_m0   = (const float*)d_in[8];
    const float* b_m0   = (const float*)d_in[9];
    const float* g_m0   = (const float*)d_in[10];
    const float* be_m0  = (const float*)d_in[11];
    const float* W_m1   = (const float*)d_in[12];
    const float* b_m1   = (const float*)d_in[13];
    const float* g_m1   = (const float*)d_in[14];
    const float* be_m1  = (const float*)d_in[15];
    const float* W_m2   = (const float*)d_in[16];
    const float* b_m2   = (const float*)d_in[17];
    float* out = (float*)d_out;

    const int N = in_sizes[0] / IN_D;   // 50000
    const int E = in_sizes[1] / 2;      // 800000
    const int* src = eidx;
    const int* dst = eidx + E;

    char* p = (char*)d_ws;
    auto alloc = [&](size_t bytes) {
        void* r = (void*)p;
        p += (bytes + 255) & ~(size_t)255;
        return r;
    };
    int*    hist   = (int*)alloc((size_t)N * 4);
    int*    rowptr = (int*)alloc((size_t)(N + 1) * 4);
    int*    cursor = (int*)alloc((size_t)N * 4);
    int*    ssort  = (int*)alloc((size_t)E * 4);
    int*    dsort  = (int*)alloc((size_t)E * 4);
    int*    esort  = (int*)alloc((size_t)E * 4);
    float*  dinv   = (float*)alloc((size_t)N * 4);
    float*  B2     = (float*)alloc((size_t)N * HIDD * 4);   // h0, later agg2
    float*  B3     = (float*)alloc((size_t)N * HIDD * 4);   // hW1, later hW2
    float*  B4     = (float*)alloc((size_t)N * HIDD * 4);   // agg1, later AB
    float*  z1     = (float*)alloc((size_t)E * 32 * 4);
    float*  Wc     = (float*)alloc(64 * 128 * 4);
    double* st0    = (double*)alloc(128 * 8);
    double* st1    = (double*)alloc(64 * 8);
    float*  s0     = (float*)alloc(64 * 4);
    float*  t0     = (float*)alloc(64 * 4);
    float*  s1v    = (float*)alloc(32 * 4);
    float*  t1v    = (float*)alloc(32 * 4);

    float* h0   = B2;  float* agg2 = B2;
    float* hW1  = B3;  float* hW2  = B3;
    float* agg1 = B4;  float* AB   = B4;

    const int nbE = (E + 255) / 256;

    // CSR build (dst-sorted) + dinv
    init_kernel<<<(N + 255) / 256, 256, 0, stream>>>(hist, st0, st1, N);
    hist_kernel<<<nbE, 256, 0, stream>>>(dst, hist, E);
    scan_kernel<<<1, 1024, 0, stream>>>(hist, rowptr, cursor, dinv, N, E);
    fill_kernel<<<nbE, 256, 0, stream>>>(src, dst, cursor, ssort, dsort, esort, E);

    // embedding: h0 = x @ W_emb + b_emb
    mm_kernel<256, 128, false, true><<<(N + 63) / 64, 512, 0, stream>>>(x, W_emb, b_emb, h0, N);

    // GCN1
    mm_kernel<128, 128, false, false><<<(N + 63) / 64, 512, 0, stream>>>(h0, W_g1, nullptr, hW1, N);
    agg_kernel<128><<<(N + 7) / 8, 256, 0, stream>>>(hW1, dinv, rowptr, ssort, b_g1, agg1, N);

    // GCN2 (relu on agg1 fused into GEMM staging)
    mm_kernel<128, 64, true, false><<<(N + 63) / 64, 256, 0, stream>>>(agg1, W_g2, nullptr, hW2, N);
    agg_kernel<64><<<(N + 15) / 16, 256, 0, stream>>>(hW2, dinv, rowptr, ssort, b_g2, agg2, N);

    // AB = h2 @ [Wtop|Wbot]  (edge MLP layer-0 factorization)
    concat_w_kernel<<<32, 256, 0, stream>>>(W_m0, Wc);
    mm_kernel<64, 128, false, false><<<(N + 63) / 64, 512, 0, stream>>>(agg2, Wc, nullptr, AB, N);

    // BN0 stats (dst-sorted, block-contiguous -> B side caches)
    {
        const int NB = 1024;
        int EB = (E + NB - 1) / NB;
        EB = (EB + 15) & ~15;
        z0stats_kernel<<<NB, 256, 0, stream>>>(AB, ssort, dsort, b_m0, st0, E, EB);
    }
    bnprep0_kernel<<<1, 64, 0, stream>>>(st0, g_m0, be_m0, s0, t0, E);

    // MLP1 (edge-tile GEMM) -> z1 (sorted order), BN1 stats fused
    mlp1_fused_kernel<<<(E + 127) / 128, 256, 0, stream>>>(AB, ssort, dsort, b_m0,
                                                           s0, t0, W_m1, b_m1, z1, st1, E);
    bnprep1_kernel<<<1, 32, 0, stream>>>(st1, g_m1, be_m1, s1v, t1v, E);

    // MLP2 + sigmoid, scatter to original edge order
    mlp2_kernel<<<nbE, 256, 0, stream>>>(z1, esort, s1v, t1v, W_m2, b_m2, out, E);
}